// Round 3
// baseline (310.395 us; speedup 1.0000x reference)
//
#include <hip/hip_runtime.h>
#include <stdint.h>

#define NW   2048
#define OBS  512
#define HS   512
#define HS2  512
#define HM   256
#define CTX  128
#define ACT  18
#define RPB  4      // rows per block
#define T    512    // threads per block

// ---------------- threefry2x32 (key = (0,42)), 20 rounds ----------------
#define TFR(x0, x1, R) { x0 += x1; x1 = (x1 << R) | (x1 >> (32 - R)); x1 ^= x0; }

__device__ __forceinline__ void threefry_0_42(uint32_t x0, uint32_t x1,
                                              uint32_t& o0, uint32_t& o1) {
    const uint32_t ks0 = 0u;
    const uint32_t ks1 = 42u;
    const uint32_t ks2 = 0x1BD11BDAu ^ ks0 ^ ks1;
    x0 += ks0; x1 += ks1;
    TFR(x0, x1, 13) TFR(x0, x1, 15) TFR(x0, x1, 26) TFR(x0, x1, 6)
    x0 += ks1; x1 += ks2 + 1u;
    TFR(x0, x1, 17) TFR(x0, x1, 29) TFR(x0, x1, 16) TFR(x0, x1, 24)
    x0 += ks2; x1 += ks0 + 2u;
    TFR(x0, x1, 13) TFR(x0, x1, 15) TFR(x0, x1, 26) TFR(x0, x1, 6)
    x0 += ks0; x1 += ks1 + 3u;
    TFR(x0, x1, 17) TFR(x0, x1, 29) TFR(x0, x1, 16) TFR(x0, x1, 24)
    x0 += ks1; x1 += ks2 + 4u;
    TFR(x0, x1, 13) TFR(x0, x1, 15) TFR(x0, x1, 26) TFR(x0, x1, 6)
    x0 += ks2; x1 += ks0 + 5u;
    o0 = x0; o1 = x1;
}

// jax_threefry_partitionable=True scheme (verified round 2): counter=(0,n),
// 32-bit output = out0 ^ out1.
__device__ __forceinline__ float gumbel_ra(int row, int a) {
    uint32_t n = (uint32_t)(row * ACT + a);
    uint32_t o0, o1;
    threefry_0_42(0u, n, o0, o1);
    uint32_t bits = o0 ^ o1;
    uint32_t fb = (bits >> 9) | 0x3F800000u;
    float f = __uint_as_float(fb) - 1.0f;            // uniform [0,1)
    const float tiny = 1.17549435e-38f;
    float u = (f < tiny) ? tiny : f;
    return -logf(-logf(u));
}

// branch-free fast tanh via native exp; saturates correctly (exp->inf/0)
__device__ __forceinline__ float fast_tanh(float x) {
    float e = __expf(2.0f * x);
    return 1.0f - 2.0f / (e + 1.0f);
}
__device__ __forceinline__ float fast_sig(float x) {
    return 1.0f / (1.0f + __expf(-x));
}

__global__ __launch_bounds__(T, 4) void iamgru_policy_kernel(
    const float* __restrict__ obs,   const float* __restrict__ hmem,
    const float* __restrict__ W1,    const float* __restrict__ b1,
    const float* __restrict__ Wc,    const float* __restrict__ bc,
    const float* __restrict__ Wa,    const float* __restrict__ ba,
    const float* __restrict__ W_ih,  const float* __restrict__ b_ih,
    const float* __restrict__ W_hh,  const float* __restrict__ b_hh,
    const float* __restrict__ W2,    const float* __restrict__ b2,
    const float* __restrict__ Wact,  const float* __restrict__ bact,
    const float* __restrict__ Wcrit, const float* __restrict__ bcrit,
    float* __restrict__ out)
{
    __shared__ float s_obs[RPB][OBS];     // 8 KB
    __shared__ float s_h[RPB][HM];        // 4 KB
    __shared__ float s_feat[RPB][HS];     // 8 KB
    __shared__ float s_hterm[RPB][CTX];   // 2 KB
    __shared__ float s_buf[RPB][HS];      // 8 KB (alog, later out2)
    __shared__ float s_wc0[CTX];
    __shared__ float s_wa[CTX];
    __shared__ float s_x[RPB];

    const int tid  = threadIdx.x;
    const int row0 = blockIdx.x * RPB;

    // ---- stage 0: stage obs + h into LDS (coalesced) ----
    for (int i = tid; i < RPB * OBS; i += T) {
        int r = i >> 9, o = i & (OBS - 1);
        s_obs[r][o] = obs[(row0 + r) * OBS + o];
    }
    for (int i = tid; i < RPB * HM; i += T) {
        int r = i >> 8, m = i & (HM - 1);
        s_h[r][m] = hmem[(row0 + r) * HM + m];
    }
    if (tid < CTX) { s_wc0[tid] = Wc[tid * (HM + 1)]; s_wa[tid] = Wa[tid]; }
    __syncthreads();

    // ---- stage 1: feat = relu(obs @ W1^T + b1), thread = output col ----
    {
        const int c = tid;
        float acc[RPB];
        float bias = b1[c];
        #pragma unroll
        for (int r = 0; r < RPB; ++r) acc[r] = bias;
        const float4* w4 = (const float4*)&W1[c * OBS];
        #pragma unroll 4
        for (int k4 = 0; k4 < OBS / 4; ++k4) {
            float4 w = w4[k4];
            #pragma unroll
            for (int r = 0; r < RPB; ++r) {
                float4 o = *(const float4*)&s_obs[r][k4 * 4];
                acc[r] += o.x * w.x; acc[r] += o.y * w.y;
                acc[r] += o.z * w.z; acc[r] += o.w * w.w;
            }
        }
        #pragma unroll
        for (int r = 0; r < RPB; ++r) s_feat[r][c] = fmaxf(acc[r], 0.0f);
    }

    // ---- stage 2: h_term = h @ Wc[:,1:]^T + bc (threads 0..127) ----
    if (tid < CTX) {
        const int c = tid;
        const float* w = &Wc[c * (HM + 1) + 1];   // stride-257 rows, keep scalar
        float acc[RPB];
        float bias = bc[c];
        #pragma unroll
        for (int r = 0; r < RPB; ++r) acc[r] = bias;
        for (int m = 0; m < HM; ++m) {
            float wv = w[m];
            #pragma unroll
            for (int r = 0; r < RPB; ++r) acc[r] += s_h[r][m] * wv;
        }
        #pragma unroll
        for (int r = 0; r < RPB; ++r) s_hterm[r][c] = acc[r];
    }
    __syncthreads();

    // ---- stage 3: alog[r][o] = ba + sum_c Wa[c]*tanh(obs*Wc0[c] + hterm) ----
    {
        const float ba0 = ba[0];
        const int o = tid;
        float ob[RPB], acc[RPB];
        #pragma unroll
        for (int r = 0; r < RPB; ++r) { ob[r] = s_obs[r][o]; acc[r] = 0.0f; }
        for (int c = 0; c < CTX; ++c) {
            float wc0 = s_wc0[c], wa = s_wa[c];
            #pragma unroll
            for (int r = 0; r < RPB; ++r)
                acc[r] += wa * fast_tanh(fmaf(ob[r], wc0, s_hterm[r][c]));
        }
        #pragma unroll
        for (int r = 0; r < RPB; ++r) s_buf[r][o] = acc[r] + ba0;
    }
    __syncthreads();

    // ---- stage 4: softmax over o + dset -> x[r] (wave per row, waves 0..3) ----
    {
        const int w = tid >> 6, lane = tid & 63;
        if (w < RPB) {
            const int r = w;
            float m = -1e30f;
            for (int o = lane; o < OBS; o += 64) m = fmaxf(m, s_buf[r][o]);
            #pragma unroll
            for (int d = 32; d >= 1; d >>= 1) m = fmaxf(m, __shfl_xor(m, d));
            float se = 0.0f, sw = 0.0f;
            for (int o = lane; o < OBS; o += 64) {
                float e = __expf(s_buf[r][o] - m);
                se += e; sw += e * s_obs[r][o];
            }
            #pragma unroll
            for (int d = 32; d >= 1; d >>= 1) { se += __shfl_xor(se, d); sw += __shfl_xor(sw, d); }
            if (lane == 0) s_x[r] = sw / se;
        }
    }
    __syncthreads();

    // ---- stage 5: GRU. thread = (gate col j, row-half); 2 rows each ----
    {
        const int j = tid & (HM - 1);
        const int half = tid >> 8;           // 0 or 1
        const int rbase = half * 2;          // rows rbase, rbase+1
        float accr[2], accz[2], accn[2];
        float bhr = b_hh[j], bhz = b_hh[HM + j], bhn = b_hh[2 * HM + j];
        #pragma unroll
        for (int q = 0; q < 2; ++q) { accr[q] = bhr; accz[q] = bhz; accn[q] = bhn; }
        const float4* wr4 = (const float4*)&W_hh[j * HM];
        const float4* wz4 = (const float4*)&W_hh[(HM + j) * HM];
        const float4* wn4 = (const float4*)&W_hh[(2 * HM + j) * HM];
        #pragma unroll 2
        for (int k4 = 0; k4 < HM / 4; ++k4) {
            float4 wr = wr4[k4], wz = wz4[k4], wn = wn4[k4];
            #pragma unroll
            for (int q = 0; q < 2; ++q) {
                float4 hv = *(const float4*)&s_h[rbase + q][k4 * 4];
                accr[q] += hv.x * wr.x; accr[q] += hv.y * wr.y;
                accr[q] += hv.z * wr.z; accr[q] += hv.w * wr.w;
                accz[q] += hv.x * wz.x; accz[q] += hv.y * wz.y;
                accz[q] += hv.z * wz.z; accz[q] += hv.w * wz.w;
                accn[q] += hv.x * wn.x; accn[q] += hv.y * wn.y;
                accn[q] += hv.z * wn.z; accn[q] += hv.w * wn.w;
            }
        }
        float wih_r = W_ih[j], wih_z = W_ih[HM + j], wih_n = W_ih[2 * HM + j];
        float bih_r = b_ih[j], bih_z = b_ih[HM + j], bih_n = b_ih[2 * HM + j];
        float hnew[2];
        #pragma unroll
        for (int q = 0; q < 2; ++q) {
            const int r = rbase + q;
            float x  = s_x[r];
            float hp = s_h[r][j];
            float rg = fast_sig(fmaf(x, wih_r, bih_r) + accr[q]);
            float zg = fast_sig(fmaf(x, wih_z, bih_z) + accz[q]);
            float ng = fast_tanh(fmaf(x, wih_n, bih_n) + rg * accn[q]);
            hnew[q] = (1.0f - zg) * ng + zg * hp;
        }
        __syncthreads();                       // all hp reads done
        #pragma unroll
        for (int q = 0; q < 2; ++q) s_h[rbase + q][j] = hnew[q];
    }
    __syncthreads();

    // ---- stage 6: out2 = relu([feat, hnew] @ W2^T + b2), thread = col ----
    {
        const int c = tid;
        float acc[RPB];
        float bias = b2[c];
        #pragma unroll
        for (int r = 0; r < RPB; ++r) acc[r] = bias;
        const float4* w4 = (const float4*)&W2[c * (HS + HM)];
        #pragma unroll 4
        for (int k4 = 0; k4 < HS / 4; ++k4) {
            float4 w = w4[k4];
            #pragma unroll
            for (int r = 0; r < RPB; ++r) {
                float4 f = *(const float4*)&s_feat[r][k4 * 4];
                acc[r] += f.x * w.x; acc[r] += f.y * w.y;
                acc[r] += f.z * w.z; acc[r] += f.w * w.w;
            }
        }
        const float4* wh4 = (const float4*)&W2[c * (HS + HM) + HS];
        #pragma unroll 4
        for (int k4 = 0; k4 < HM / 4; ++k4) {
            float4 w = wh4[k4];
            #pragma unroll
            for (int r = 0; r < RPB; ++r) {
                float4 h = *(const float4*)&s_h[r][k4 * 4];
                acc[r] += h.x * w.x; acc[r] += h.y * w.y;
                acc[r] += h.z * w.z; acc[r] += h.w * w.w;
            }
        }
        #pragma unroll
        for (int r = 0; r < RPB; ++r) s_buf[r][c] = fmaxf(acc[r], 0.0f);
    }
    __syncthreads();

    // ---- stage 7: heads + categorical sampling ----
    // waves 0..3: logits+action+logprob for row w; waves 4..7: value for row w-4
    {
        const int w = tid >> 6, lane = tid & 63;
        if (w < RPB) {
            const int r = w;
            const int grow = row0 + r;
            float4 x0 = *(const float4*)&s_buf[r][lane * 8];
            float4 x1 = *(const float4*)&s_buf[r][lane * 8 + 4];
            float la[ACT];
            #pragma unroll
            for (int a = 0; a < ACT; ++a) {
                const float4* wa4 = (const float4*)&Wact[a * HS2 + lane * 8];
                float4 w0 = wa4[0], w1 = wa4[1];
                float p = x0.x * w0.x + x0.y * w0.y + x0.z * w0.z + x0.w * w0.w
                        + x1.x * w1.x + x1.y * w1.y + x1.z * w1.z + x1.w * w1.w;
                #pragma unroll
                for (int d = 32; d >= 1; d >>= 1) p += __shfl_xor(p, d);
                la[a] = p + bact[a];
            }
            float g = (lane < ACT) ? gumbel_ra(grow, lane) : 0.0f;
            float best = -1e30f; int amax = 0;
            float mx = -1e30f;
            #pragma unroll
            for (int a = 0; a < ACT; ++a) {
                float g_ = __shfl(g, a);
                float y = la[a] + g_;
                if (y > best) { best = y; amax = a; }   // first-max tie-break
                mx = fmaxf(mx, la[a]);
            }
            float se = 0.0f;
            #pragma unroll
            for (int a = 0; a < ACT; ++a) se += __expf(la[a] - mx);
            float lse = mx + logf(se);
            float lp = la[amax] - lse;
            if (lane == 0) {
                out[grow]          = (float)amax;  // action
                out[2 * NW + grow] = lp;           // log_prob
            }
        } else {
            const int r = w - RPB;
            const int grow = row0 + r;
            float4 x0 = *(const float4*)&s_buf[r][lane * 8];
            float4 x1 = *(const float4*)&s_buf[r][lane * 8 + 4];
            const float4* wc4 = (const float4*)&Wcrit[lane * 8];
            float4 w0 = wc4[0], w1 = wc4[1];
            float p = x0.x * w0.x + x0.y * w0.y + x0.z * w0.z + x0.w * w0.w
                    + x1.x * w1.x + x1.y * w1.y + x1.z * w1.z + x1.w * w1.w;
            #pragma unroll
            for (int d = 32; d >= 1; d >>= 1) p += __shfl_xor(p, d);
            if (lane == 0) out[NW + grow] = p + bcrit[0];   // value
        }
    }
}

extern "C" void kernel_launch(void* const* d_in, const int* in_sizes, int n_in,
                              void* d_out, int out_size, void* d_ws, size_t ws_size,
                              hipStream_t stream) {
    const float* obs   = (const float*)d_in[0];
    const float* hmem  = (const float*)d_in[1];
    const float* W1    = (const float*)d_in[2];
    const float* b1    = (const float*)d_in[3];
    const float* Wc    = (const float*)d_in[4];
    const float* bc    = (const float*)d_in[5];
    const float* Wa    = (const float*)d_in[6];
    const float* ba    = (const float*)d_in[7];
    const float* W_ih  = (const float*)d_in[8];
    const float* b_ih  = (const float*)d_in[9];
    const float* W_hh  = (const float*)d_in[10];
    const float* b_hh  = (const float*)d_in[11];
    const float* W2    = (const float*)d_in[12];
    const float* b2    = (const float*)d_in[13];
    const float* Wact  = (const float*)d_in[14];
    const float* bact  = (const float*)d_in[15];
    const float* Wcrit = (const float*)d_in[16];
    const float* bcrit = (const float*)d_in[17];

    iamgru_policy_kernel<<<NW / RPB, T, 0, stream>>>(
        obs, hmem, W1, b1, Wc, bc, Wa, ba, W_ih, b_ih, W_hh, b_hh,
        W2, b2, Wact, bact, Wcrit, bcrit, (float*)d_out);
}

// Round 4
// 165.593 us; speedup vs baseline: 1.8744x; 1.8744x over previous
//
#include <hip/hip_runtime.h>
#include <stdint.h>

#define NW   2048
#define OBS  512
#define HS   512
#define HS2  512
#define HM   256
#define CTX  128
#define ACT  18
#define RPB  4      // rows per block
#define T    512    // threads per block

// ws layout (floats)
#define W1T_OFF   0                      // [512][512]  W1T[k][c] = W1[c][k]
#define WCT_OFF   262144                 // [256][128]  WcT[m][c] = Wc[c][1+m]
#define WHHT_OFF  294912                 // [256][768]  WhhT[m][g*256+j] = W_hh[g*256+j][m]
#define W2T_OFF   491520                 // [768][512]  W2T[k][c] = W2[c][k]

// ---------------- threefry2x32 (key = (0,42)), 20 rounds ----------------
#define TFR(x0, x1, R) { x0 += x1; x1 = (x1 << R) | (x1 >> (32 - R)); x1 ^= x0; }

__device__ __forceinline__ void threefry_0_42(uint32_t x0, uint32_t x1,
                                              uint32_t& o0, uint32_t& o1) {
    const uint32_t ks0 = 0u;
    const uint32_t ks1 = 42u;
    const uint32_t ks2 = 0x1BD11BDAu ^ ks0 ^ ks1;
    x0 += ks0; x1 += ks1;
    TFR(x0, x1, 13) TFR(x0, x1, 15) TFR(x0, x1, 26) TFR(x0, x1, 6)
    x0 += ks1; x1 += ks2 + 1u;
    TFR(x0, x1, 17) TFR(x0, x1, 29) TFR(x0, x1, 16) TFR(x0, x1, 24)
    x0 += ks2; x1 += ks0 + 2u;
    TFR(x0, x1, 13) TFR(x0, x1, 15) TFR(x0, x1, 26) TFR(x0, x1, 6)
    x0 += ks0; x1 += ks1 + 3u;
    TFR(x0, x1, 17) TFR(x0, x1, 29) TFR(x0, x1, 16) TFR(x0, x1, 24)
    x0 += ks1; x1 += ks2 + 4u;
    TFR(x0, x1, 13) TFR(x0, x1, 15) TFR(x0, x1, 26) TFR(x0, x1, 6)
    x0 += ks2; x1 += ks0 + 5u;
    o0 = x0; o1 = x1;
}

// jax_threefry_partitionable scheme (verified round 2): counter=(0,n), out0^out1
__device__ __forceinline__ float gumbel_ra(int row, int a) {
    uint32_t n = (uint32_t)(row * ACT + a);
    uint32_t o0, o1;
    threefry_0_42(0u, n, o0, o1);
    uint32_t bits = o0 ^ o1;
    uint32_t fb = (bits >> 9) | 0x3F800000u;
    float f = __uint_as_float(fb) - 1.0f;
    const float tiny = 1.17549435e-38f;
    float u = (f < tiny) ? tiny : f;
    return -logf(-logf(u));
}

__device__ __forceinline__ float fast_tanh(float x) {
    float e = __expf(2.0f * x);
    return 1.0f - 2.0f / (e + 1.0f);
}
__device__ __forceinline__ float fast_sig(float x) {
    return 1.0f / (1.0f + __expf(-x));
}

// ---- generic 32x32 LDS-tiled transpose of 4 weight matrices into ws ----
// out[j][i] = in[i*ld + off + j]
__global__ __launch_bounds__(256) void transpose_weights(
    const float* __restrict__ W1, const float* __restrict__ Wc,
    const float* __restrict__ Whh, const float* __restrict__ W2,
    float* __restrict__ ws)
{
    int b = blockIdx.x;
    const float* src; float* dst; int ld, off, R, it, jt;
    if (b < 256)      { src = W1;  dst = ws + W1T_OFF;  ld = 512; off = 0; it = b >> 4; jt = b & 15; R = 512; }
    else if (b < 288) { b -= 256; src = Wc;  dst = ws + WCT_OFF;  ld = 257; off = 1; it = b >> 3; jt = b & 7;  R = 128; }
    else if (b < 480) { b -= 288; src = Whh; dst = ws + WHHT_OFF; ld = 256; off = 0; it = b / 8;  jt = b % 8;  R = 768; }
    else              { b -= 480; src = W2;  dst = ws + W2T_OFF;  ld = 768; off = 0; it = b / 24; jt = b % 24; R = 512; }
    __shared__ float t[32][33];
    const int tx = threadIdx.x & 31, ty = threadIdx.x >> 5;   // 32 x 8
    const int i0 = it * 32, j0 = jt * 32;
    #pragma unroll
    for (int q = 0; q < 4; ++q)
        t[ty + 8 * q][tx] = src[(i0 + ty + 8 * q) * ld + off + j0 + tx];
    __syncthreads();
    #pragma unroll
    for (int q = 0; q < 4; ++q)
        dst[(j0 + ty + 8 * q) * R + i0 + tx] = t[tx][ty + 8 * q];
}

__global__ __launch_bounds__(T) void iamgru_policy_kernel(
    const float* __restrict__ obs,   const float* __restrict__ hmem,
    const float* __restrict__ b1,
    const float* __restrict__ Wc,    const float* __restrict__ bc,
    const float* __restrict__ Wa,    const float* __restrict__ ba,
    const float* __restrict__ W_ih,  const float* __restrict__ b_ih,
    const float* __restrict__ b_hh,  const float* __restrict__ b2,
    const float* __restrict__ Wact,  const float* __restrict__ bact,
    const float* __restrict__ Wcrit, const float* __restrict__ bcrit,
    const float* __restrict__ ws,
    float* __restrict__ out)
{
    const float* W1T  = ws + W1T_OFF;
    const float* WcT  = ws + WCT_OFF;
    const float* WhhT = ws + WHHT_OFF;
    const float* W2T  = ws + W2T_OFF;

    __shared__ float s_obs[RPB][OBS];     // 8 KB
    __shared__ float s_h[RPB][HM];        // 4 KB
    __shared__ float s_feat[RPB][HS];     // 8 KB
    __shared__ float s_hterm[RPB][CTX];   // 2 KB
    __shared__ float s_buf[RPB][HS];      // 8 KB (stage-2 partials, alog, out2)
    __shared__ float s_wc0[CTX];
    __shared__ float s_wa[CTX];
    __shared__ float s_x[RPB];

    const int tid  = threadIdx.x;
    const int row0 = blockIdx.x * RPB;

    // ---- stage 0: stage obs + h into LDS (coalesced) ----
    for (int i = tid; i < RPB * OBS; i += T) {
        int r = i >> 9, o = i & (OBS - 1);
        s_obs[r][o] = obs[(row0 + r) * OBS + o];
    }
    for (int i = tid; i < RPB * HM; i += T) {
        int r = i >> 8, m = i & (HM - 1);
        s_h[r][m] = hmem[(row0 + r) * HM + m];
    }
    if (tid < CTX) { s_wc0[tid] = Wc[tid * (HM + 1)]; s_wa[tid] = Wa[tid]; }
    __syncthreads();

    // ---- stage 1: feat = relu(obs @ W1^T + b1); thread=c, coalesced W1T ----
    {
        const int c = tid;
        float acc[RPB];
        float bias = b1[c];
        #pragma unroll
        for (int r = 0; r < RPB; ++r) acc[r] = bias;
        const float* wp = &W1T[c];
        #pragma unroll 2
        for (int k4 = 0; k4 < OBS / 4; ++k4) {
            float4 o0 = *(const float4*)&s_obs[0][k4 * 4];
            float4 o1 = *(const float4*)&s_obs[1][k4 * 4];
            float4 o2 = *(const float4*)&s_obs[2][k4 * 4];
            float4 o3 = *(const float4*)&s_obs[3][k4 * 4];
            float w0 = wp[(k4 * 4 + 0) * HS];
            float w1 = wp[(k4 * 4 + 1) * HS];
            float w2 = wp[(k4 * 4 + 2) * HS];
            float w3 = wp[(k4 * 4 + 3) * HS];
            acc[0] = fmaf(o0.x, w0, acc[0]); acc[0] = fmaf(o0.y, w1, acc[0]);
            acc[0] = fmaf(o0.z, w2, acc[0]); acc[0] = fmaf(o0.w, w3, acc[0]);
            acc[1] = fmaf(o1.x, w0, acc[1]); acc[1] = fmaf(o1.y, w1, acc[1]);
            acc[1] = fmaf(o1.z, w2, acc[1]); acc[1] = fmaf(o1.w, w3, acc[1]);
            acc[2] = fmaf(o2.x, w0, acc[2]); acc[2] = fmaf(o2.y, w1, acc[2]);
            acc[2] = fmaf(o2.z, w2, acc[2]); acc[2] = fmaf(o2.w, w3, acc[2]);
            acc[3] = fmaf(o3.x, w0, acc[3]); acc[3] = fmaf(o3.y, w1, acc[3]);
            acc[3] = fmaf(o3.z, w2, acc[3]); acc[3] = fmaf(o3.w, w3, acc[3]);
        }
        #pragma unroll
        for (int r = 0; r < RPB; ++r) s_feat[r][c] = fmaxf(acc[r], 0.0f);
    }

    // ---- stage 2: h_term partials; all threads; 4-way k-split over m ----
    {
        const int c = tid & (CTX - 1);
        const int g = tid >> 7;              // m-range [g*64, g*64+64)
        float acc[RPB] = {0.f, 0.f, 0.f, 0.f};
        const float* wp = &WcT[c];
        #pragma unroll 2
        for (int m4 = 0; m4 < 16; ++m4) {
            int m = g * 64 + m4 * 4;
            float4 h0 = *(const float4*)&s_h[0][m];
            float4 h1 = *(const float4*)&s_h[1][m];
            float4 h2 = *(const float4*)&s_h[2][m];
            float4 h3 = *(const float4*)&s_h[3][m];
            float w0 = wp[(m + 0) * CTX];
            float w1 = wp[(m + 1) * CTX];
            float w2 = wp[(m + 2) * CTX];
            float w3 = wp[(m + 3) * CTX];
            acc[0] = fmaf(h0.x, w0, acc[0]); acc[0] = fmaf(h0.y, w1, acc[0]);
            acc[0] = fmaf(h0.z, w2, acc[0]); acc[0] = fmaf(h0.w, w3, acc[0]);
            acc[1] = fmaf(h1.x, w0, acc[1]); acc[1] = fmaf(h1.y, w1, acc[1]);
            acc[1] = fmaf(h1.z, w2, acc[1]); acc[1] = fmaf(h1.w, w3, acc[1]);
            acc[2] = fmaf(h2.x, w0, acc[2]); acc[2] = fmaf(h2.y, w1, acc[2]);
            acc[2] = fmaf(h2.z, w2, acc[2]); acc[2] = fmaf(h2.w, w3, acc[2]);
            acc[3] = fmaf(h3.x, w0, acc[3]); acc[3] = fmaf(h3.y, w1, acc[3]);
            acc[3] = fmaf(h3.z, w2, acc[3]); acc[3] = fmaf(h3.w, w3, acc[3]);
        }
        #pragma unroll
        for (int r = 0; r < RPB; ++r) s_buf[r][g * CTX + c] = acc[r];
    }
    __syncthreads();
    if (tid < CTX) {
        #pragma unroll
        for (int r = 0; r < RPB; ++r)
            s_hterm[r][tid] = bc[tid] + s_buf[r][tid] + s_buf[r][CTX + tid]
                            + s_buf[r][2 * CTX + tid] + s_buf[r][3 * CTX + tid];
    }
    __syncthreads();

    // ---- stage 3: alog[r][o] = ba + sum_c Wa[c]*tanh(obs*Wc0[c] + hterm) ----
    {
        const float ba0 = ba[0];
        const int o = tid;
        float ob[RPB], acc[RPB];
        #pragma unroll
        for (int r = 0; r < RPB; ++r) { ob[r] = s_obs[r][o]; acc[r] = 0.0f; }
        for (int c4 = 0; c4 < CTX / 4; ++c4) {
            float4 wc = *(const float4*)&s_wc0[c4 * 4];
            float4 wa = *(const float4*)&s_wa[c4 * 4];
            float4 ht0 = *(const float4*)&s_hterm[0][c4 * 4];
            float4 ht1 = *(const float4*)&s_hterm[1][c4 * 4];
            float4 ht2 = *(const float4*)&s_hterm[2][c4 * 4];
            float4 ht3 = *(const float4*)&s_hterm[3][c4 * 4];
            acc[0] += wa.x * fast_tanh(fmaf(ob[0], wc.x, ht0.x));
            acc[0] += wa.y * fast_tanh(fmaf(ob[0], wc.y, ht0.y));
            acc[0] += wa.z * fast_tanh(fmaf(ob[0], wc.z, ht0.z));
            acc[0] += wa.w * fast_tanh(fmaf(ob[0], wc.w, ht0.w));
            acc[1] += wa.x * fast_tanh(fmaf(ob[1], wc.x, ht1.x));
            acc[1] += wa.y * fast_tanh(fmaf(ob[1], wc.y, ht1.y));
            acc[1] += wa.z * fast_tanh(fmaf(ob[1], wc.z, ht1.z));
            acc[1] += wa.w * fast_tanh(fmaf(ob[1], wc.w, ht1.w));
            acc[2] += wa.x * fast_tanh(fmaf(ob[2], wc.x, ht2.x));
            acc[2] += wa.y * fast_tanh(fmaf(ob[2], wc.y, ht2.y));
            acc[2] += wa.z * fast_tanh(fmaf(ob[2], wc.z, ht2.z));
            acc[2] += wa.w * fast_tanh(fmaf(ob[2], wc.w, ht2.w));
            acc[3] += wa.x * fast_tanh(fmaf(ob[3], wc.x, ht3.x));
            acc[3] += wa.y * fast_tanh(fmaf(ob[3], wc.y, ht3.y));
            acc[3] += wa.z * fast_tanh(fmaf(ob[3], wc.z, ht3.z));
            acc[3] += wa.w * fast_tanh(fmaf(ob[3], wc.w, ht3.w));
        }
        #pragma unroll
        for (int r = 0; r < RPB; ++r) s_buf[r][o] = acc[r] + ba0;
    }
    __syncthreads();

    // ---- stage 4: softmax over o + dset -> x[r] (wave per row) ----
    {
        const int w = tid >> 6, lane = tid & 63;
        if (w < RPB) {
            const int r = w;
            float m = -1e30f;
            for (int o = lane; o < OBS; o += 64) m = fmaxf(m, s_buf[r][o]);
            #pragma unroll
            for (int d = 32; d >= 1; d >>= 1) m = fmaxf(m, __shfl_xor(m, d));
            float se = 0.0f, sw = 0.0f;
            for (int o = lane; o < OBS; o += 64) {
                float e = __expf(s_buf[r][o] - m);
                se += e; sw += e * s_obs[r][o];
            }
            #pragma unroll
            for (int d = 32; d >= 1; d >>= 1) { se += __shfl_xor(se, d); sw += __shfl_xor(sw, d); }
            if (lane == 0) s_x[r] = sw / se;
        }
    }
    __syncthreads();

    // ---- stage 5: GRU; thread=(gate col j, row-half), coalesced WhhT ----
    {
        const int j = tid & (HM - 1);
        const int half = tid >> 8;
        const int rbase = half * 2;
        float accr[2], accz[2], accn[2];
        float bhr = b_hh[j], bhz = b_hh[HM + j], bhn = b_hh[2 * HM + j];
        accr[0] = accr[1] = bhr; accz[0] = accz[1] = bhz; accn[0] = accn[1] = bhn;
        const float* wp = &WhhT[j];
        #pragma unroll 2
        for (int m4 = 0; m4 < HM / 4; ++m4) {
            float4 h0 = *(const float4*)&s_h[rbase][m4 * 4];
            float4 h1 = *(const float4*)&s_h[rbase + 1][m4 * 4];
            float e0[4] = {h0.x, h0.y, h0.z, h0.w};
            float e1[4] = {h1.x, h1.y, h1.z, h1.w};
            #pragma unroll
            for (int kk = 0; kk < 4; ++kk) {
                int m = m4 * 4 + kk;
                float wr = wp[m * 768];
                float wz = wp[m * 768 + 256];
                float wn = wp[m * 768 + 512];
                accr[0] = fmaf(e0[kk], wr, accr[0]); accr[1] = fmaf(e1[kk], wr, accr[1]);
                accz[0] = fmaf(e0[kk], wz, accz[0]); accz[1] = fmaf(e1[kk], wz, accz[1]);
                accn[0] = fmaf(e0[kk], wn, accn[0]); accn[1] = fmaf(e1[kk], wn, accn[1]);
            }
        }
        float wih_r = W_ih[j], wih_z = W_ih[HM + j], wih_n = W_ih[2 * HM + j];
        float bih_r = b_ih[j], bih_z = b_ih[HM + j], bih_n = b_ih[2 * HM + j];
        float hnew[2];
        #pragma unroll
        for (int q = 0; q < 2; ++q) {
            const int r = rbase + q;
            float x  = s_x[r];
            float hp = s_h[r][j];
            float rg = fast_sig(fmaf(x, wih_r, bih_r) + accr[q]);
            float zg = fast_sig(fmaf(x, wih_z, bih_z) + accz[q]);
            float ng = fast_tanh(fmaf(x, wih_n, bih_n) + rg * accn[q]);
            hnew[q] = (1.0f - zg) * ng + zg * hp;
        }
        __syncthreads();                       // all hp reads done
        #pragma unroll
        for (int q = 0; q < 2; ++q) s_h[rbase + q][j] = hnew[q];
    }
    __syncthreads();

    // ---- stage 6: out2 = relu([feat, hnew] @ W2^T + b2); coalesced W2T ----
    {
        const int c = tid;
        float acc[RPB];
        float bias = b2[c];
        #pragma unroll
        for (int r = 0; r < RPB; ++r) acc[r] = bias;
        const float* wp = &W2T[c];
        #pragma unroll 2
        for (int k4 = 0; k4 < HS / 4; ++k4) {
            float4 f0 = *(const float4*)&s_feat[0][k4 * 4];
            float4 f1 = *(const float4*)&s_feat[1][k4 * 4];
            float4 f2 = *(const float4*)&s_feat[2][k4 * 4];
            float4 f3 = *(const float4*)&s_feat[3][k4 * 4];
            float w0 = wp[(k4 * 4 + 0) * HS2];
            float w1 = wp[(k4 * 4 + 1) * HS2];
            float w2 = wp[(k4 * 4 + 2) * HS2];
            float w3 = wp[(k4 * 4 + 3) * HS2];
            acc[0] = fmaf(f0.x, w0, acc[0]); acc[0] = fmaf(f0.y, w1, acc[0]);
            acc[0] = fmaf(f0.z, w2, acc[0]); acc[0] = fmaf(f0.w, w3, acc[0]);
            acc[1] = fmaf(f1.x, w0, acc[1]); acc[1] = fmaf(f1.y, w1, acc[1]);
            acc[1] = fmaf(f1.z, w2, acc[1]); acc[1] = fmaf(f1.w, w3, acc[1]);
            acc[2] = fmaf(f2.x, w0, acc[2]); acc[2] = fmaf(f2.y, w1, acc[2]);
            acc[2] = fmaf(f2.z, w2, acc[2]); acc[2] = fmaf(f2.w, w3, acc[2]);
            acc[3] = fmaf(f3.x, w0, acc[3]); acc[3] = fmaf(f3.y, w1, acc[3]);
            acc[3] = fmaf(f3.z, w2, acc[3]); acc[3] = fmaf(f3.w, w3, acc[3]);
        }
        #pragma unroll 2
        for (int m4 = 0; m4 < HM / 4; ++m4) {
            float4 h0 = *(const float4*)&s_h[0][m4 * 4];
            float4 h1 = *(const float4*)&s_h[1][m4 * 4];
            float4 h2 = *(const float4*)&s_h[2][m4 * 4];
            float4 h3 = *(const float4*)&s_h[3][m4 * 4];
            float w0 = wp[(HS + m4 * 4 + 0) * HS2];
            float w1 = wp[(HS + m4 * 4 + 1) * HS2];
            float w2 = wp[(HS + m4 * 4 + 2) * HS2];
            float w3 = wp[(HS + m4 * 4 + 3) * HS2];
            acc[0] = fmaf(h0.x, w0, acc[0]); acc[0] = fmaf(h0.y, w1, acc[0]);
            acc[0] = fmaf(h0.z, w2, acc[0]); acc[0] = fmaf(h0.w, w3, acc[0]);
            acc[1] = fmaf(h1.x, w0, acc[1]); acc[1] = fmaf(h1.y, w1, acc[1]);
            acc[1] = fmaf(h1.z, w2, acc[1]); acc[1] = fmaf(h1.w, w3, acc[1]);
            acc[2] = fmaf(h2.x, w0, acc[2]); acc[2] = fmaf(h2.y, w1, acc[2]);
            acc[2] = fmaf(h2.z, w2, acc[2]); acc[2] = fmaf(h2.w, w3, acc[2]);
            acc[3] = fmaf(h3.x, w0, acc[3]); acc[3] = fmaf(h3.y, w1, acc[3]);
            acc[3] = fmaf(h3.z, w2, acc[3]); acc[3] = fmaf(h3.w, w3, acc[3]);
        }
        #pragma unroll
        for (int r = 0; r < RPB; ++r) s_buf[r][c] = fmaxf(acc[r], 0.0f);
    }
    __syncthreads();

    // ---- stage 7: heads + categorical sampling ----
    {
        const int w = tid >> 6, lane = tid & 63;
        if (w < RPB) {
            const int r = w;
            const int grow = row0 + r;
            float4 x0 = *(const float4*)&s_buf[r][lane * 8];
            float4 x1 = *(const float4*)&s_buf[r][lane * 8 + 4];
            float la[ACT];
            #pragma unroll
            for (int a = 0; a < ACT; ++a) {
                const float4* wa4 = (const float4*)&Wact[a * HS2 + lane * 8];
                float4 w0 = wa4[0], w1 = wa4[1];
                float p = x0.x * w0.x + x0.y * w0.y + x0.z * w0.z + x0.w * w0.w
                        + x1.x * w1.x + x1.y * w1.y + x1.z * w1.z + x1.w * w1.w;
                #pragma unroll
                for (int d = 32; d >= 1; d >>= 1) p += __shfl_xor(p, d);
                la[a] = p + bact[a];
            }
            float g = (lane < ACT) ? gumbel_ra(grow, lane) : 0.0f;
            float best = -1e30f; int amax = 0;
            float mx = -1e30f;
            #pragma unroll
            for (int a = 0; a < ACT; ++a) {
                float g_ = __shfl(g, a);
                float y = la[a] + g_;
                if (y > best) { best = y; amax = a; }
                mx = fmaxf(mx, la[a]);
            }
            float se = 0.0f;
            #pragma unroll
            for (int a = 0; a < ACT; ++a) se += __expf(la[a] - mx);
            float lse = mx + logf(se);
            float lp = la[amax] - lse;
            if (lane == 0) {
                out[grow]          = (float)amax;
                out[2 * NW + grow] = lp;
            }
        } else {
            const int r = w - RPB;
            const int grow = row0 + r;
            float4 x0 = *(const float4*)&s_buf[r][lane * 8];
            float4 x1 = *(const float4*)&s_buf[r][lane * 8 + 4];
            const float4* wc4 = (const float4*)&Wcrit[lane * 8];
            float4 w0 = wc4[0], w1 = wc4[1];
            float p = x0.x * w0.x + x0.y * w0.y + x0.z * w0.z + x0.w * w0.w
                    + x1.x * w1.x + x1.y * w1.y + x1.z * w1.z + x1.w * w1.w;
            #pragma unroll
            for (int d = 32; d >= 1; d >>= 1) p += __shfl_xor(p, d);
            if (lane == 0) out[NW + grow] = p + bcrit[0];
        }
    }
}

extern "C" void kernel_launch(void* const* d_in, const int* in_sizes, int n_in,
                              void* d_out, int out_size, void* d_ws, size_t ws_size,
                              hipStream_t stream) {
    const float* obs   = (const float*)d_in[0];
    const float* hmem  = (const float*)d_in[1];
    const float* W1    = (const float*)d_in[2];
    const float* b1    = (const float*)d_in[3];
    const float* Wc    = (const float*)d_in[4];
    const float* bc    = (const float*)d_in[5];
    const float* Wa    = (const float*)d_in[6];
    const float* ba    = (const float*)d_in[7];
    const float* W_ih  = (const float*)d_in[8];
    const float* b_ih  = (const float*)d_in[9];
    const float* W_hh  = (const float*)d_in[10];
    const float* b_hh  = (const float*)d_in[11];
    const float* W2    = (const float*)d_in[12];
    const float* b2    = (const float*)d_in[13];
    const float* Wact  = (const float*)d_in[14];
    const float* bact  = (const float*)d_in[15];
    const float* Wcrit = (const float*)d_in[16];
    const float* bcrit = (const float*)d_in[17];
    float* ws = (float*)d_ws;

    transpose_weights<<<864, 256, 0, stream>>>(W1, Wc, W_hh, W2, ws);

    iamgru_policy_kernel<<<NW / RPB, T, 0, stream>>>(
        obs, hmem, b1, Wc, bc, Wa, ba, W_ih, b_ih, b_hh,
        b2, Wact, bact, Wcrit, bcrit, ws, (float*)d_out);
}